// Round 10
// baseline (224.491 us; speedup 1.0000x reference)
//
#include <hip/hip_runtime.h>
#include <hip/hip_cooperative_groups.h>
#include <math.h>

namespace cg = cooperative_groups;

#define N_TOK 4096
#define DMODEL 512
#define NH 8
#define HD 64

typedef __attribute__((ext_vector_type(4))) float f32x4;
typedef __attribute__((ext_vector_type(8))) _Float16 f16x8;
typedef __attribute__((ext_vector_type(4))) _Float16 f16x4;

#define MFMA16(A, B, C) __builtin_amdgcn_mfma_f32_16x16x32_f16(A, B, C, 0, 0, 0)

// XOR-swizzle for 64-col f16 tiles (validated: conflicts 5.24M -> 0).
#define SWZ(r, c) (((r) * 64) + ((c) ^ (((r) & 7) << 3)))

// =====================================================================
// R20: single cooperative kernel, 256 blocks x 1024 thr, 80 KB LDS.
// Phase 1 = R8 qkv (threads >=768 idle), phase 2 = R8 flash, phase 3 =
// R9 out. grid.sync() between phases (device-scope fence for cross-XCD
// visibility). Bodies byte-identical to the proven standalone kernels —
// the experiment isolates kernel-boundary overhead (2 drains + ramps).
// =====================================================================
__global__ __launch_bounds__(1024) void fused_attn(
    const float* __restrict__ x,
    const float* __restrict__ Wq, const float* __restrict__ bq,
    const float* __restrict__ Wk, const float* __restrict__ bk,
    const float* __restrict__ Wv, const float* __restrict__ bv,
    const float* __restrict__ Wo, const float* __restrict__ bo,
    float* __restrict__ out,
    _Float16* __restrict__ Q16, _Float16* __restrict__ K16,
    _Float16* __restrict__ VT16, _Float16* __restrict__ OP,
    float* __restrict__ LS) {
    __shared__ __align__(16) _Float16 smem[40960];   // 80 KB, reused per phase
    cg::grid_group grid = cg::this_grid();

    int t = threadIdx.x;
    int w = t >> 6, l = t & 63, quad = l >> 4, ln = l & 15;
    int b = blockIdx.x;

    // ---------------- phase 1: fused cast + QKV GEMM (768 active thr) --------
    {
        _Float16* AsB = smem;            // [2][128][64]
        _Float16* WsB = smem + 16384;    // [2][3][64][64]

        int z = w >> 2, ww = w & 3;
        int n0 = (b & 31) * 128, o0 = (b >> 5) * 64;
        int h = o0 >> 6;
        bool act = (t < 768);

        const float* biasz = (z == 0) ? bq : (z == 1) ? bk : bv;

        f32x4 acc[2][4] = {};

        bool isA = (t < 256);
        int asr = t >> 3, asc = (t & 7) * 8;
        int tt = t - 256;
        int wr = tt >> 3, wc = (tt & 7) * 8;
        int axc = asc ^ ((asr & 7) << 3);
        int wxc = wc ^ ((wr & 7) << 3);

        const float* Abase = x + (size_t)n0 * DMODEL;
        const float* W0 = Wq + (size_t)o0 * DMODEL;
        const float* W1 = Wk + (size_t)o0 * DMODEL;
        const float* W2 = Wv + (size_t)o0 * DMODEL;

        f32x4 pa[4][2];
        f32x4 pw[3][2];
        if (isA) {
#pragma unroll
            for (int r = 0; r < 4; r++) {
                pa[r][0] = *(const f32x4*)&Abase[(size_t)(asr + r * 32) * DMODEL + asc];
                pa[r][1] = *(const f32x4*)&Abase[(size_t)(asr + r * 32) * DMODEL + asc + 4];
            }
        } else if (act) {
            pw[0][0] = *(const f32x4*)&W0[(size_t)wr * DMODEL + wc];
            pw[0][1] = *(const f32x4*)&W0[(size_t)wr * DMODEL + wc + 4];
            pw[1][0] = *(const f32x4*)&W1[(size_t)wr * DMODEL + wc];
            pw[1][1] = *(const f32x4*)&W1[(size_t)wr * DMODEL + wc + 4];
            pw[2][0] = *(const f32x4*)&W2[(size_t)wr * DMODEL + wc];
            pw[2][1] = *(const f32x4*)&W2[(size_t)wr * DMODEL + wc + 4];
        }

        for (int it = 0; it < 8; it++) {
            int p = it & 1;
            if (isA) {
#pragma unroll
                for (int r = 0; r < 4; r++) {
                    f16x8 av = {(_Float16)pa[r][0][0], (_Float16)pa[r][0][1],
                                (_Float16)pa[r][0][2], (_Float16)pa[r][0][3],
                                (_Float16)pa[r][1][0], (_Float16)pa[r][1][1],
                                (_Float16)pa[r][1][2], (_Float16)pa[r][1][3]};
                    *(f16x8*)&AsB[(size_t)(p * 128 + asr + r * 32) * 64 + axc] = av;
                }
            } else if (act) {
#pragma unroll
                for (int zt = 0; zt < 3; zt++) {
                    f16x8 wv_ = {(_Float16)pw[zt][0][0], (_Float16)pw[zt][0][1],
                                 (_Float16)pw[zt][0][2], (_Float16)pw[zt][0][3],
                                 (_Float16)pw[zt][1][0], (_Float16)pw[zt][1][1],
                                 (_Float16)pw[zt][1][2], (_Float16)pw[zt][1][3]};
                    *(f16x8*)&WsB[(size_t)((p * 3 + zt) * 64 + wr) * 64 + wxc] = wv_;
                }
            }
            __syncthreads();

            int k1 = (it + 1) * 64;
            if (k1 < DMODEL) {
                if (isA) {
#pragma unroll
                    for (int r = 0; r < 4; r++) {
                        pa[r][0] = *(const f32x4*)&Abase[(size_t)(asr + r * 32) * DMODEL + k1 + asc];
                        pa[r][1] = *(const f32x4*)&Abase[(size_t)(asr + r * 32) * DMODEL + k1 + asc + 4];
                    }
                } else if (act) {
                    pw[0][0] = *(const f32x4*)&W0[(size_t)wr * DMODEL + k1 + wc];
                    pw[0][1] = *(const f32x4*)&W0[(size_t)wr * DMODEL + k1 + wc + 4];
                    pw[1][0] = *(const f32x4*)&W1[(size_t)wr * DMODEL + k1 + wc];
                    pw[1][1] = *(const f32x4*)&W1[(size_t)wr * DMODEL + k1 + wc + 4];
                    pw[2][0] = *(const f32x4*)&W2[(size_t)wr * DMODEL + k1 + wc];
                    pw[2][1] = *(const f32x4*)&W2[(size_t)wr * DMODEL + k1 + wc + 4];
                }
            }

            if (act) {
#pragma unroll
                for (int ks = 0; ks < 2; ks++) {
                    int xc = (ks * 32 + quad * 8) ^ ((ln & 7) << 3);
                    f16x8 af0 = *(const f16x8*)&AsB[(size_t)(p * 128 + ww * 32 + ln) * 64 + xc];
                    f16x8 af1 = *(const f16x8*)&AsB[(size_t)(p * 128 + ww * 32 + 16 + ln) * 64 + xc];
#pragma unroll
                    for (int c = 0; c < 4; c++) {
                        f16x8 bf = *(const f16x8*)&WsB[(size_t)((p * 3 + z) * 64 + c * 16 + ln) * 64 + xc];
                        acc[0][c] = MFMA16(af0, bf, acc[0][c]);
                        acc[1][c] = MFMA16(af1, bf, acc[1][c]);
                    }
                }
            }
        }

        __syncthreads();

        const float QS = 0.125f * 1.44269504088896340736f;
        _Float16* Qs = smem;             // 128x72
        _Float16* Ksep = smem + 9216;    // 128x72
        _Float16* Vt = smem + 18432;     // 64x136

        if (act) {
            if (z < 2) {
                _Float16* st = (z == 0) ? Qs : Ksep;
                float sc_ = (z == 0) ? QS : 1.0f;
#pragma unroll
                for (int c = 0; c < 4; c++) {
                    float bv_ = biasz[o0 + c * 16 + ln];
#pragma unroll
                    for (int rt = 0; rt < 2; rt++)
#pragma unroll
                        for (int i = 0; i < 4; i++) {
                            int lr = ww * 32 + rt * 16 + quad * 4 + i;
                            st[(size_t)lr * 72 + c * 16 + ln] =
                                (_Float16)((acc[rt][c][i] + bv_) * sc_);
                        }
                }
            } else {
#pragma unroll
                for (int c = 0; c < 4; c++) {
                    float bv_ = biasz[o0 + c * 16 + ln];
#pragma unroll
                    for (int rt = 0; rt < 2; rt++)
#pragma unroll
                        for (int i = 0; i < 4; i++) {
                            int np = (ww >> 1) * 64 + (ww & 1) * 32 + quad * 8 + rt * 4 + i;
                            Vt[(size_t)(c * 16 + ln) * 136 + np] = (_Float16)(acc[rt][c][i] + bv_);
                        }
                }
            }
        }
        __syncthreads();

        if (t < 256) {
#pragma unroll
            for (int k = 0; k < 4; k++) {
                int row = k * 32 + (t >> 3), col = (t & 7) * 8;
                *(f16x8*)&Q16[((size_t)h * N_TOK + n0 + row) * HD + col] =
                    *(const f16x8*)&Qs[(size_t)row * 72 + col];
            }
        } else if (t < 512) {
            int u = t - 256;
#pragma unroll
            for (int k = 0; k < 4; k++) {
                int row = k * 32 + (u >> 3), col = (u & 7) * 8;
                *(f16x8*)&K16[((size_t)h * N_TOK + n0 + row) * HD + col] =
                    *(const f16x8*)&Ksep[(size_t)row * 72 + col];
            }
        } else if (t < 768) {
            int u = t - 512;
#pragma unroll
            for (int k = 0; k < 4; k++) {
                int d = k * 16 + (u >> 4), col = (u & 15) * 8;
                *(f16x8*)&VT16[((size_t)h * HD + d) * N_TOK + n0 + col] =
                    *(const f16x8*)&Vt[(size_t)d * 136 + col];
            }
        }
    }

    grid.sync();   // Q16/K16/VT16 visible device-wide

    // ---------------- phase 2: flash attention (R8 body, BK=128) -------------
    {
        _Float16* KsB = smem;            // [2][2][64*64] = 16384 f16
        _Float16* VsB = smem + 16384;    // [2][2][64*64]

        int h = b & 7;
        int qt = (b >> 3) & 7;
        int s = b >> 6;
        int q0 = qt * 512 + w * 32;
        int m_start = s * 1024;

        f16x8 qf[2][2];
#pragma unroll
        for (int rt = 0; rt < 2; rt++) {
            const _Float16* qp = &Q16[((size_t)h * N_TOK + q0 + rt * 16 + ln) * HD + quad * 8];
            qf[rt][0] = *(const f16x8*)qp;
            qf[rt][1] = *(const f16x8*)(qp + 32);
        }

        f16x8 ones;
#pragma unroll
        for (int j = 0; j < 8; j++) ones[j] = (_Float16)1.0f;

        f32x4 oacc[2][4] = {};
        f32x4 lacc[2] = {};

        const _Float16* kbase = K16 + (size_t)h * N_TOK * HD;
        const _Float16* vbase = VT16 + (size_t)h * HD * N_TOK;
        int g = t >> 9, tt = t & 511;
        int krow = tt >> 2, kcol = (tt & 3) * 16;
        int vrow = tt >> 3, vcol = (tt & 7) * 16;

        f16x8 pk0, pk1;
        if (g == 0) {
            const _Float16* src = kbase + (size_t)(m_start + krow) * HD + kcol;
            pk0 = *(const f16x8*)src;
            pk1 = *(const f16x8*)(src + 8);
        } else {
            const _Float16* src = vbase + (size_t)vrow * N_TOK + m_start + vcol;
            pk0 = *(const f16x8*)src;
            pk1 = *(const f16x8*)(src + 8);
        }

        for (int it = 0; it < 8; it++) {
            int m0 = m_start + it * 128;
            int p = it & 1;
            if (g == 0) {
                _Float16* dst = KsB + (size_t)(p * 2 + (krow >> 6)) * 4096;
                int r64 = krow & 63;
                *(f16x8*)&dst[SWZ(r64, kcol)] = pk0;
                *(f16x8*)&dst[SWZ(r64, kcol + 8)] = pk1;
            } else {
                _Float16* dst = VsB + (size_t)(p * 2 + (vcol >> 6)) * 4096;
                int c64 = vcol & 63;
                *(f16x8*)&dst[SWZ(vrow, c64)] = pk0;
                *(f16x8*)&dst[SWZ(vrow, c64 + 8)] = pk1;
            }
            __syncthreads();

            if (it < 7) {
                int m1 = m0 + 128;
                if (g == 0) {
                    const _Float16* src = kbase + (size_t)(m1 + krow) * HD + kcol;
                    pk0 = *(const f16x8*)src;
                    pk1 = *(const f16x8*)(src + 8);
                } else {
                    const _Float16* src = vbase + (size_t)vrow * N_TOK + m1 + vcol;
                    pk0 = *(const f16x8*)src;
                    pk1 = *(const f16x8*)(src + 8);
                }
            }

#pragma unroll
            for (int kh = 0; kh < 2; kh++) {
                const _Float16* Kt = KsB + (size_t)(p * 2 + kh) * 4096;
                const _Float16* Vt = VsB + (size_t)(p * 2 + kh) * 4096;

                f16x8 kb[4][2], vb[4][2];
#pragma unroll
                for (int c = 0; c < 4; c++) {
                    kb[c][0] = *(const f16x8*)&Kt[SWZ(c * 16 + ln, quad * 8)];
                    kb[c][1] = *(const f16x8*)&Kt[SWZ(c * 16 + ln, 32 + quad * 8)];
                    vb[c][0] = *(const f16x8*)&Vt[SWZ(c * 16 + ln, quad * 8)];
                    vb[c][1] = *(const f16x8*)&Vt[SWZ(c * 16 + ln, 32 + quad * 8)];
                }

                f16x8 bf[2][2];
#pragma unroll
                for (int rt = 0; rt < 2; rt++) {
                    f32x4 sacc[4] = {};
#pragma unroll
                    for (int kk = 0; kk < 4; kk++) {
                        sacc[kk] = MFMA16(kb[kk][0], qf[rt][0], sacc[kk]);
                        sacc[kk] = MFMA16(kb[kk][1], qf[rt][1], sacc[kk]);
                    }
#pragma unroll
                    for (int kk = 0; kk < 4; kk++) {
                        bf[rt][kk >> 1][(kk & 1) * 4 + 0] = (_Float16)__builtin_exp2f(sacc[kk][0]);
                        bf[rt][kk >> 1][(kk & 1) * 4 + 1] = (_Float16)__builtin_exp2f(sacc[kk][1]);
                        bf[rt][kk >> 1][(kk & 1) * 4 + 2] = (_Float16)__builtin_exp2f(sacc[kk][2]);
                        bf[rt][kk >> 1][(kk & 1) * 4 + 3] = (_Float16)__builtin_exp2f(sacc[kk][3]);
                    }
                }

#pragma unroll
                for (int rt = 0; rt < 2; rt++) {
                    lacc[rt] = MFMA16(ones, bf[rt][0], lacc[rt]);
                    lacc[rt] = MFMA16(ones, bf[rt][1], lacc[rt]);
                }

#pragma unroll
                for (int c = 0; c < 4; c++) {
                    oacc[0][c] = MFMA16(vb[c][0], bf[0][0], oacc[0][c]);
                    oacc[0][c] = MFMA16(vb[c][1], bf[0][1], oacc[0][c]);
                    oacc[1][c] = MFMA16(vb[c][0], bf[1][0], oacc[1][c]);
                    oacc[1][c] = MFMA16(vb[c][1], bf[1][1], oacc[1][c]);
                }
            }
        }

        _Float16* obase = OP + (size_t)s * N_TOK * DMODEL;
#pragma unroll
        for (int rt = 0; rt < 2; rt++) {
            int r = q0 + rt * 16 + ln;
#pragma unroll
            for (int c = 0; c < 4; c++) {
                f16x4 ov = {(_Float16)oacc[rt][c][0], (_Float16)oacc[rt][c][1],
                            (_Float16)oacc[rt][c][2], (_Float16)oacc[rt][c][3]};
                *(f16x4*)&obase[(size_t)r * DMODEL + h * HD + c * 16 + quad * 4] = ov;
            }
        }
        if (l < 16) {
#pragma unroll
            for (int rt = 0; rt < 2; rt++) {
                int r = q0 + rt * 16 + ln;
                LS[((size_t)s * NH + h) * N_TOK + r] = lacc[rt][0];
            }
        }
    }

    grid.sync();   // OP/LS visible device-wide

    // ---------------- phase 3: output GEMM (R9 1024-thr body) ----------------
    {
        _Float16* AsB = smem;            // [2][128][64]
        _Float16* WsB = smem + 16384;    // [2][64][64]

        int r16 = w & 7, ch = w >> 3;
        int n0 = (b & 31) * 128, o0 = (b >> 5) * 64;
        int sr = t >> 3, sc = (t & 7) * 8;
        int sxc = sc ^ ((sr & 7) << 3);
        int tw = t & 511;
        int wr = tw >> 3, wc = (tw & 7) * 8;
        int wxc = wc ^ ((wr & 7) << 3);
        bool isW = (t < 512);
        const size_t PSTR = (size_t)N_TOK * DMODEL;

        f32x4 acc[2] = {};

        const float* Wbase = Wo + (size_t)o0 * DMODEL;

        f16x8 pa[4];
        float lt;
        f32x4 pw0, pw1;
        {
            size_t base = (size_t)(n0 + sr) * DMODEL + sc;
#pragma unroll
            for (int s_ = 0; s_ < 4; s_++)
                pa[s_] = *(const f16x8*)&OP[s_ * PSTR + base];
            const float* ls = LS + n0 + sr;
            lt = (ls[0] + ls[NH * N_TOK]) + (ls[2 * NH * N_TOK] + ls[3 * NH * N_TOK]);
            if (isW) {
                pw0 = *(const f32x4*)&Wbase[(size_t)wr * DMODEL + wc];
                pw1 = *(const f32x4*)&Wbase[(size_t)wr * DMODEL + wc + 4];
            }
        }

        for (int it = 0; it < 8; it++) {
            int p = it & 1;
            {
                float inv = 1.0f / lt;
                f16x8 s0;
#pragma unroll
                for (int j = 0; j < 8; j++) {
                    s0[j] = (_Float16)(
                        ((((float)pa[0][j] + (float)pa[1][j]) +
                          ((float)pa[2][j] + (float)pa[3][j]))) * inv);
                }
                *(f16x8*)&AsB[(size_t)(p * 128 + sr) * 64 + sxc] = s0;
                if (isW) {
                    f16x8 wv_ = {(_Float16)pw0[0], (_Float16)pw0[1], (_Float16)pw0[2],
                                 (_Float16)pw0[3], (_Float16)pw1[0], (_Float16)pw1[1],
                                 (_Float16)pw1[2], (_Float16)pw1[3]};
                    *(f16x8*)&WsB[(size_t)(p * 64 + wr) * 64 + wxc] = wv_;
                }
            }
            __syncthreads();

            int k1 = (it + 1) * 64;
            if (k1 < DMODEL) {
                int h1 = k1 >> 6;
                size_t base = (size_t)(n0 + sr) * DMODEL + k1 + sc;
#pragma unroll
                for (int s_ = 0; s_ < 4; s_++)
                    pa[s_] = *(const f16x8*)&OP[s_ * PSTR + base];
                const float* ls = LS + (size_t)h1 * N_TOK + n0 + sr;
                lt = (ls[0] + ls[NH * N_TOK]) + (ls[2 * NH * N_TOK] + ls[3 * NH * N_TOK]);
                if (isW) {
                    pw0 = *(const f32x4*)&Wbase[(size_t)wr * DMODEL + k1 + wc];
                    pw1 = *(const f32x4*)&Wbase[(size_t)wr * DMODEL + k1 + wc + 4];
                }
            }

#pragma unroll
            for (int ks = 0; ks < 2; ks++) {
                int xc = (ks * 32 + quad * 8) ^ ((ln & 7) << 3);
                f16x8 af = *(const f16x8*)&AsB[(size_t)(p * 128 + r16 * 16 + ln) * 64 + xc];
#pragma unroll
                for (int c = 0; c < 2; c++) {
                    f16x8 bf = *(const f16x8*)&WsB[(size_t)(p * 64 + ch * 32 + c * 16 + ln) * 64 + xc];
                    acc[c] = MFMA16(af, bf, acc[c]);
                }
            }
        }

#pragma unroll
        for (int c = 0; c < 2; c++) {
            float bv_ = bo[o0 + ch * 32 + c * 16 + ln];
#pragma unroll
            for (int i = 0; i < 4; i++) {
                int r = n0 + r16 * 16 + quad * 4 + i;
                out[(size_t)r * DMODEL + o0 + ch * 32 + c * 16 + ln] = acc[c][i] + bv_;
            }
        }
    }
}

// =====================================================================
// Fallback standalone kernels (exact R8/R9 proven versions)
// =====================================================================
__global__ __launch_bounds__(768) void qkv_gemm(const float* __restrict__ x,
                                                const float* __restrict__ Wq,
                                                const float* __restrict__ bq,
                                                const float* __restrict__ Wk,
                                                const float* __restrict__ bk,
                                                const float* __restrict__ Wv,
                                                const float* __restrict__ bv,
                                                _Float16* __restrict__ Q16,
                                                _Float16* __restrict__ K16,
                                                _Float16* __restrict__ VT16) {
    __shared__ __align__(16) _Float16 smem[40960];
    _Float16* AsB = smem;
    _Float16* WsB = smem + 16384;

    int t = threadIdx.x;
    int w = t >> 6, l = t & 63, quad = l >> 4, ln = l & 15;
    int z = w >> 2, ww = w & 3;
    int n0 = blockIdx.x * 128, o0 = blockIdx.y * 64;
    int h = o0 >> 6;

    const float* biasz = (z == 0) ? bq : (z == 1) ? bk : bv;

    f32x4 acc[2][4] = {};

    bool isA = (t < 256);
    int asr = t >> 3, asc = (t & 7) * 8;
    int tt = t - 256;
    int wr = tt >> 3, wc = (tt & 7) * 8;
    int axc = asc ^ ((asr & 7) << 3);
    int wxc = wc ^ ((wr & 7) << 3);

    const float* Abase = x + (size_t)n0 * DMODEL;
    const float* W0 = Wq + (size_t)o0 * DMODEL;
    const float* W1 = Wk + (size_t)o0 * DMODEL;
    const float* W2 = Wv + (size_t)o0 * DMODEL;

    f32x4 pa[4][2];
    f32x4 pw[3][2];
    if (isA) {
#pragma unroll
        for (int r = 0; r < 4; r++) {
            pa[r][0] = *(const f32x4*)&Abase[(size_t)(asr + r * 32) * DMODEL + asc];
            pa[r][1] = *(const f32x4*)&Abase[(size_t)(asr + r * 32) * DMODEL + asc + 4];
        }
    } else {
        pw[0][0] = *(const f32x4*)&W0[(size_t)wr * DMODEL + wc];
        pw[0][1] = *(const f32x4*)&W0[(size_t)wr * DMODEL + wc + 4];
        pw[1][0] = *(const f32x4*)&W1[(size_t)wr * DMODEL + wc];
        pw[1][1] = *(const f32x4*)&W1[(size_t)wr * DMODEL + wc + 4];
        pw[2][0] = *(const f32x4*)&W2[(size_t)wr * DMODEL + wc];
        pw[2][1] = *(const f32x4*)&W2[(size_t)wr * DMODEL + wc + 4];
    }

    for (int it = 0; it < 8; it++) {
        int p = it & 1;
        if (isA) {
#pragma unroll
            for (int r = 0; r < 4; r++) {
                f16x8 av = {(_Float16)pa[r][0][0], (_Float16)pa[r][0][1],
                            (_Float16)pa[r][0][2], (_Float16)pa[r][0][3],
                            (_Float16)pa[r][1][0], (_Float16)pa[r][1][1],
                            (_Float16)pa[r][1][2], (_Float16)pa[r][1][3]};
                *(f16x8*)&AsB[(size_t)(p * 128 + asr + r * 32) * 64 + axc] = av;
            }
        } else {
#pragma unroll
            for (int zt = 0; zt < 3; zt++) {
                f16x8 wv_ = {(_Float16)pw[zt][0][0], (_Float16)pw[zt][0][1],
                             (_Float16)pw[zt][0][2], (_Float16)pw[zt][0][3],
                             (_Float16)pw[zt][1][0], (_Float16)pw[zt][1][1],
                             (_Float16)pw[zt][1][2], (_Float16)pw[zt][1][3]};
                *(f16x8*)&WsB[(size_t)((p * 3 + zt) * 64 + wr) * 64 + wxc] = wv_;
            }
        }
        __syncthreads();

        int k1 = (it + 1) * 64;
        if (k1 < DMODEL) {
            if (isA) {
#pragma unroll
                for (int r = 0; r < 4; r++) {
                    pa[r][0] = *(const f32x4*)&Abase[(size_t)(asr + r * 32) * DMODEL + k1 + asc];
                    pa[r][1] = *(const f32x4*)&Abase[(size_t)(asr + r * 32) * DMODEL + k1 + asc + 4];
                }
            } else {
                pw[0][0] = *(const f32x4*)&W0[(size_t)wr * DMODEL + k1 + wc];
                pw[0][1] = *(const f32x4*)&W0[(size_t)wr * DMODEL + k1 + wc + 4];
                pw[1][0] = *(const f32x4*)&W1[(size_t)wr * DMODEL + k1 + wc];
                pw[1][1] = *(const f32x4*)&W1[(size_t)wr * DMODEL + k1 + wc + 4];
                pw[2][0] = *(const f32x4*)&W2[(size_t)wr * DMODEL + k1 + wc];
                pw[2][1] = *(const f32x4*)&W2[(size_t)wr * DMODEL + k1 + wc + 4];
            }
        }

#pragma unroll
        for (int ks = 0; ks < 2; ks++) {
            int xc = (ks * 32 + quad * 8) ^ ((ln & 7) << 3);
            f16x8 af0 = *(const f16x8*)&AsB[(size_t)(p * 128 + ww * 32 + ln) * 64 + xc];
            f16x8 af1 = *(const f16x8*)&AsB[(size_t)(p * 128 + ww * 32 + 16 + ln) * 64 + xc];
#pragma unroll
            for (int c = 0; c < 4; c++) {
                f16x8 bf = *(const f16x8*)&WsB[(size_t)((p * 3 + z) * 64 + c * 16 + ln) * 64 + xc];
                acc[0][c] = MFMA16(af0, bf, acc[0][c]);
                acc[1][c] = MFMA16(af1, bf, acc[1][c]);
            }
        }
    }

    __syncthreads();

    const float QS = 0.125f * 1.44269504088896340736f;
    _Float16* Qs = smem;
    _Float16* Ksep = smem + 9216;
    _Float16* Vt = smem + 18432;

    if (z < 2) {
        _Float16* st = (z == 0) ? Qs : Ksep;
        float sc_ = (z == 0) ? QS : 1.0f;
#pragma unroll
        for (int c = 0; c < 4; c++) {
            float bv_ = biasz[o0 + c * 16 + ln];
#pragma unroll
            for (int rt = 0; rt < 2; rt++)
#pragma unroll
                for (int i = 0; i < 4; i++) {
                    int lr = ww * 32 + rt * 16 + quad * 4 + i;
                    st[(size_t)lr * 72 + c * 16 + ln] =
                        (_Float16)((acc[rt][c][i] + bv_) * sc_);
                }
        }
    } else {
#pragma unroll
        for (int c = 0; c < 4; c++) {
            float bv_ = biasz[o0 + c * 16 + ln];
#pragma unroll
            for (int rt = 0; rt < 2; rt++)
#pragma unroll
                for (int i = 0; i < 4; i++) {
                    int np = (ww >> 1) * 64 + (ww & 1) * 32 + quad * 8 + rt * 4 + i;
                    Vt[(size_t)(c * 16 + ln) * 136 + np] = (_Float16)(acc[rt][c][i] + bv_);
                }
        }
    }
    __syncthreads();

    if (t < 256) {
#pragma unroll
        for (int k = 0; k < 4; k++) {
            int row = k * 32 + (t >> 3), col = (t & 7) * 8;
            *(f16x8*)&Q16[((size_t)h * N_TOK + n0 + row) * HD + col] =
                *(const f16x8*)&Qs[(size_t)row * 72 + col];
        }
    } else if (t < 512) {
        int u = t - 256;
#pragma unroll
        for (int k = 0; k < 4; k++) {
            int row = k * 32 + (u >> 3), col = (u & 7) * 8;
            *(f16x8*)&K16[((size_t)h * N_TOK + n0 + row) * HD + col] =
                *(const f16x8*)&Ksep[(size_t)row * 72 + col];
        }
    } else {
        int u = t - 512;
#pragma unroll
        for (int k = 0; k < 4; k++) {
            int d = k * 16 + (u >> 4), col = (u & 15) * 8;
            *(f16x8*)&VT16[((size_t)h * HD + d) * N_TOK + n0 + col] =
                *(const f16x8*)&Vt[(size_t)d * 136 + col];
        }
    }
}

__global__ __launch_bounds__(1024) void flash_mfma(const _Float16* __restrict__ Q16,
                                                   const _Float16* __restrict__ K16,
                                                   const _Float16* __restrict__ VT16,
                                                   _Float16* __restrict__ OP,
                                                   float* __restrict__ LS) {
    __shared__ __align__(16) _Float16 Ks[2][2][64 * 64];
    __shared__ __align__(16) _Float16 Vs[2][2][64 * 64];

    int t = threadIdx.x;
    int w = t >> 6, l = t & 63, quad = l >> 4, ln = l & 15;
    int bid = blockIdx.x;
    int h = bid & 7;
    int qt = (bid >> 3) & 7;
    int s = bid >> 6;
    int q0 = qt * 512 + w * 32;
    int m_start = s * 1024;

    f16x8 qf[2][2];
#pragma unroll
    for (int rt = 0; rt < 2; rt++) {
        const _Float16* qp = &Q16[((size_t)h * N_TOK + q0 + rt * 16 + ln) * HD + quad * 8];
        qf[rt][0] = *(const f16x8*)qp;
        qf[rt][1] = *(const f16x8*)(qp + 32);
    }

    f16x8 ones;
#pragma unroll
    for (int j = 0; j < 8; j++) ones[j] = (_Float16)1.0f;

    f32x4 oacc[2][4] = {};
    f32x4 lacc[2] = {};

    const _Float16* kbase = K16 + (size_t)h * N_TOK * HD;
    const _Float16* vbase = VT16 + (size_t)h * HD * N_TOK;
    int g = t >> 9, tt = t & 511;
    int krow = tt >> 2, kcol = (tt & 3) * 16;
    int vrow = tt >> 3, vcol = (tt & 7) * 16;

    f16x8 pk0, pk1;
    if (g == 0) {
        const _Float16* src = kbase + (size_t)(m_start + krow) * HD + kcol;
        pk0 = *(const f16x8*)src;
        pk1 = *(const f16x8*)(src + 8);
    } else {
        const _Float16* src = vbase + (size_t)vrow * N_TOK + m_start + vcol;
        pk0 = *(const f16x8*)src;
        pk1 = *(const f16x8*)(src + 8);
    }

    for (int it = 0; it < 8; it++) {
        int m0 = m_start + it * 128;
        int p = it & 1;
        if (g == 0) {
            _Float16* dst = &Ks[p][krow >> 6][0];
            int r64 = krow & 63;
            *(f16x8*)&dst[SWZ(r64, kcol)] = pk0;
            *(f16x8*)&dst[SWZ(r64, kcol + 8)] = pk1;
        } else {
            _Float16* dst = &Vs[p][vcol >> 6][0];
            int c64 = vcol & 63;
            *(f16x8*)&dst[SWZ(vrow, c64)] = pk0;
            *(f16x8*)&dst[SWZ(vrow, c64 + 8)] = pk1;
        }
        __syncthreads();

        if (it < 7) {
            int m1 = m0 + 128;
            if (g == 0) {
                const _Float16* src = kbase + (size_t)(m1 + krow) * HD + kcol;
                pk0 = *(const f16x8*)src;
                pk1 = *(const f16x8*)(src + 8);
            } else {
                const _Float16* src = vbase + (size_t)vrow * N_TOK + m1 + vcol;
                pk0 = *(const f16x8*)src;
                pk1 = *(const f16x8*)(src + 8);
            }
        }

#pragma unroll
        for (int kh = 0; kh < 2; kh++) {
            const _Float16* Kt = &Ks[p][kh][0];
            const _Float16* Vt = &Vs[p][kh][0];

            f16x8 kb[4][2], vb[4][2];
#pragma unroll
            for (int c = 0; c < 4; c++) {
                kb[c][0] = *(const f16x8*)&Kt[SWZ(c * 16 + ln, quad * 8)];
                kb[c][1] = *(const f16x8*)&Kt[SWZ(c * 16 + ln, 32 + quad * 8)];
                vb[c][0] = *(const f16x8*)&Vt[SWZ(c * 16 + ln, quad * 8)];
                vb[c][1] = *(const f16x8*)&Vt[SWZ(c * 16 + ln, 32 + quad * 8)];
            }

            f16x8 bf[2][2];
#pragma unroll
            for (int rt = 0; rt < 2; rt++) {
                f32x4 sacc[4] = {};
#pragma unroll
                for (int kk = 0; kk < 4; kk++) {
                    sacc[kk] = MFMA16(kb[kk][0], qf[rt][0], sacc[kk]);
                    sacc[kk] = MFMA16(kb[kk][1], qf[rt][1], sacc[kk]);
                }
#pragma unroll
                for (int kk = 0; kk < 4; kk++) {
                    bf[rt][kk >> 1][(kk & 1) * 4 + 0] = (_Float16)__builtin_exp2f(sacc[kk][0]);
                    bf[rt][kk >> 1][(kk & 1) * 4 + 1] = (_Float16)__builtin_exp2f(sacc[kk][1]);
                    bf[rt][kk >> 1][(kk & 1) * 4 + 2] = (_Float16)__builtin_exp2f(sacc[kk][2]);
                    bf[rt][kk >> 1][(kk & 1) * 4 + 3] = (_Float16)__builtin_exp2f(sacc[kk][3]);
                }
            }

#pragma unroll
            for (int rt = 0; rt < 2; rt++) {
                lacc[rt] = MFMA16(ones, bf[rt][0], lacc[rt]);
                lacc[rt] = MFMA16(ones, bf[rt][1], lacc[rt]);
            }

#pragma unroll
            for (int c = 0; c < 4; c++) {
                oacc[0][c] = MFMA16(vb[c][0], bf[0][0], oacc[0][c]);
                oacc[0][c] = MFMA16(vb[c][1], bf[0][1], oacc[0][c]);
                oacc[1][c] = MFMA16(vb[c][0], bf[1][0], oacc[1][c]);
                oacc[1][c] = MFMA16(vb[c][1], bf[1][1], oacc[1][c]);
            }
        }
    }

    _Float16* obase = OP + (size_t)s * N_TOK * DMODEL;
#pragma unroll
    for (int rt = 0; rt < 2; rt++) {
        int r = q0 + rt * 16 + ln;
#pragma unroll
        for (int c = 0; c < 4; c++) {
            f16x4 ov = {(_Float16)oacc[rt][c][0], (_Float16)oacc[rt][c][1],
                        (_Float16)oacc[rt][c][2], (_Float16)oacc[rt][c][3]};
            *(f16x4*)&obase[(size_t)r * DMODEL + h * HD + c * 16 + quad * 4] = ov;
        }
    }
    if (l < 16) {
#pragma unroll
        for (int rt = 0; rt < 2; rt++) {
            int r = q0 + rt * 16 + ln;
            LS[((size_t)s * NH + h) * N_TOK + r] = lacc[rt][0];
        }
    }
}

__global__ __launch_bounds__(1024) void out_gemm(const _Float16* __restrict__ OP,
                                                 const float* __restrict__ LS,
                                                 const float* __restrict__ Wo,
                                                 const float* __restrict__ bo,
                                                 float* __restrict__ out) {
    __shared__ __align__(16) _Float16 smem[24576];
    _Float16* AsB = smem;
    _Float16* WsB = smem + 16384;

    int t = threadIdx.x;
    int w = t >> 6, l = t & 63, quad = l >> 4, ln = l & 15;
    int r16 = w & 7, ch = w >> 3;
    int n0 = blockIdx.x * 128, o0 = blockIdx.y * 64;
    int sr = t >> 3, sc = (t & 7) * 8;
    int sxc = sc ^ ((sr & 7) << 3);
    int tw = t & 511;
    int wr = tw >> 3, wc = (tw & 7) * 8;
    int wxc = wc ^ ((wr & 7) << 3);
    bool isW = (t < 512);
    const size_t PSTR = (size_t)N_TOK * DMODEL;

    f32x4 acc[2] = {};

    const float* Wbase = Wo + (size_t)o0 * DMODEL;

    f16x8 pa[4];
    float lt;
    f32x4 pw0, pw1;
    {
        size_t base = (size_t)(n0 + sr) * DMODEL + sc;
#pragma unroll
        for (int s_ = 0; s_ < 4; s_++)
            pa[s_] = *(const f16x8*)&OP[s_ * PSTR + base];
        const float* ls = LS + n0 + sr;
        lt = (ls[0] + ls[NH * N_TOK]) + (ls[2 * NH * N_TOK] + ls[3 * NH * N_TOK]);
        if (isW) {
            pw0 = *(const f32x4*)&Wbase[(size_t)wr * DMODEL + wc];
            pw1 = *(const f32x4*)&Wbase[(size_t)wr * DMODEL + wc + 4];
        }
    }

    for (int it = 0; it < 8; it++) {
        int p = it & 1;
        {
            float inv = 1.0f / lt;
            f16x8 s0;
#pragma unroll
            for (int j = 0; j < 8; j++) {
                s0[j] = (_Float16)(
                    ((((float)pa[0][j] + (float)pa[1][j]) +
                      ((float)pa[2][j] + (float)pa[3][j]))) * inv);
            }
            *(f16x8*)&AsB[(size_t)(p * 128 + sr) * 64 + sxc] = s0;
            if (isW) {
                f16x8 wv_ = {(_Float16)pw0[0], (_Float16)pw0[1], (_Float16)pw0[2],
                             (_Float16)pw0[3], (_Float16)pw1[0], (_Float16)pw1[1],
                             (_Float16)pw1[2], (_Float16)pw1[3]};
                *(f16x8*)&WsB[(size_t)(p * 64 + wr) * 64 + wxc] = wv_;
            }
        }
        __syncthreads();

        int k1 = (it + 1) * 64;
        if (k1 < DMODEL) {
            int h1 = k1 >> 6;
            size_t base = (size_t)(n0 + sr) * DMODEL + k1 + sc;
#pragma unroll
            for (int s_ = 0; s_ < 4; s_++)
                pa[s_] = *(const f16x8*)&OP[s_ * PSTR + base];
            const float* ls = LS + (size_t)h1 * N_TOK + n0 + sr;
            lt = (ls[0] + ls[NH * N_TOK]) + (ls[2 * NH * N_TOK] + ls[3 * NH * N_TOK]);
            if (isW) {
                pw0 = *(const f32x4*)&Wbase[(size_t)wr * DMODEL + k1 + wc];
                pw1 = *(const f32x4*)&Wbase[(size_t)wr * DMODEL + k1 + wc + 4];
            }
        }

#pragma unroll
        for (int ks = 0; ks < 2; ks++) {
            int xc = (ks * 32 + quad * 8) ^ ((ln & 7) << 3);
            f16x8 af = *(const f16x8*)&AsB[(size_t)(p * 128 + r16 * 16 + ln) * 64 + xc];
#pragma unroll
            for (int c = 0; c < 2; c++) {
                f16x8 bf = *(const f16x8*)&WsB[(size_t)(p * 64 + ch * 32 + c * 16 + ln) * 64 + xc];
                acc[c] = MFMA16(af, bf, acc[c]);
            }
        }
    }

#pragma unroll
    for (int c = 0; c < 2; c++) {
        float bv_ = bo[o0 + ch * 32 + c * 16 + ln];
#pragma unroll
        for (int i = 0; i < 4; i++) {
            int r = n0 + r16 * 16 + quad * 4 + i;
            out[(size_t)r * DMODEL + o0 + ch * 32 + c * 16 + ln] = acc[c][i] + bv_;
        }
    }
}

extern "C" void kernel_launch(void* const* d_in, const int* in_sizes, int n_in,
                              void* d_out, int out_size, void* d_ws, size_t ws_size,
                              hipStream_t stream) {
    const float* x  = (const float*)d_in[0];
    const float* Wq = (const float*)d_in[1];
    const float* bq = (const float*)d_in[2];
    const float* Wk = (const float*)d_in[3];
    const float* bk = (const float*)d_in[4];
    const float* Wv = (const float*)d_in[5];
    const float* bv = (const float*)d_in[6];
    const float* Wo = (const float*)d_in[7];
    const float* bo = (const float*)d_in[8];
    float* out = (float*)d_out;

    char* ws = (char*)d_ws;
    _Float16* Q16  = (_Float16*)(ws + (4u << 20));       // 4 MB
    _Float16* K16  = (_Float16*)(ws + (8u << 20));       // 4 MB
    _Float16* VT16 = (_Float16*)(ws + (12u << 20));      // 4 MB (key-permuted, sigma)
    _Float16* OP   = (_Float16*)(ws + (16u << 20));      // 16 MB: 4 split-K partials
    float*    LSp  = (float*)   (ws + (32u << 20));      // 512 KB: [4][8][4096]

    void* args[] = {(void*)&x,  (void*)&Wq, (void*)&bq, (void*)&Wk, (void*)&bk,
                    (void*)&Wv, (void*)&bv, (void*)&Wo, (void*)&bo, (void*)&out,
                    (void*)&Q16, (void*)&K16, (void*)&VT16, (void*)&OP, (void*)&LSp};
    hipError_t err = hipLaunchCooperativeKernel((void*)fused_attn, dim3(256),
                                                dim3(1024), args, 0, stream);
    if (err != hipSuccess) {
        // fallback: proven 3-kernel path (R8/R9)
        qkv_gemm<<<dim3(32, 8), 768, 0, stream>>>(x, Wq, bq, Wk, bk, Wv, bv,
                                                  Q16, K16, VT16);
        flash_mfma<<<dim3(256), 1024, 0, stream>>>(Q16, K16, VT16, OP, LSp);
        out_gemm<<<dim3(32, 8), 1024, 0, stream>>>(OP, LSp, Wo, bo, out);
    }
}

// Round 11
// 148.464 us; speedup vs baseline: 1.5121x; 1.5121x over previous
//
#include <hip/hip_runtime.h>
#include <math.h>

#define N_TOK 4096
#define DMODEL 512
#define NH 8
#define HD 64

typedef __attribute__((ext_vector_type(4))) float f32x4;
typedef __attribute__((ext_vector_type(8))) _Float16 f16x8;
typedef __attribute__((ext_vector_type(4))) _Float16 f16x4;

#define MFMA16(A, B, C) __builtin_amdgcn_mfma_f32_16x16x32_f16(A, B, C, 0, 0, 0)

// XOR-swizzle for 64-col f16 tiles (validated: conflicts 5.24M -> 0).
#define SWZ(r, c) (((r) * 64) + ((c) ^ (((r) & 7) << 3)))
// 128-col variant: each 64-col half permutes exactly like SWZ (<=2-way verified).
#define SWZ128(r, c) (((r) * 128) + ((c) ^ (((r) & 7) << 3)))

// ---------------- fused cast + QKV GEMM: 768 thr, 12 waves, z-fused, dbuf -----
// (exact R8 code — proven)
__global__ __launch_bounds__(768) void qkv_gemm(const float* __restrict__ x,
                                                const float* __restrict__ Wq,
                                                const float* __restrict__ bq,
                                                const float* __restrict__ Wk,
                                                const float* __restrict__ bk,
                                                const float* __restrict__ Wv,
                                                const float* __restrict__ bv,
                                                _Float16* __restrict__ Q16,
                                                _Float16* __restrict__ K16,
                                                _Float16* __restrict__ VT16) {
    // [0,16384): As[2][128][64] ; [16384,40960): Ws[2][3][64][64]  (80 KB)
    __shared__ __align__(16) _Float16 smem[40960];
    _Float16* AsB = smem;
    _Float16* WsB = smem + 16384;

    int t = threadIdx.x;
    int w = t >> 6, l = t & 63, quad = l >> 4, ln = l & 15;
    int z = w >> 2, ww = w & 3;
    int n0 = blockIdx.x * 128, o0 = blockIdx.y * 64;
    int h = o0 >> 6;

    const float* biasz = (z == 0) ? bq : (z == 1) ? bk : bv;

    f32x4 acc[2][4] = {};

    bool isA = (t < 256);
    int asr = t >> 3, asc = (t & 7) * 8;
    int tt = t - 256;
    int wr = tt >> 3, wc = (tt & 7) * 8;
    int axc = asc ^ ((asr & 7) << 3);
    int wxc = wc ^ ((wr & 7) << 3);

    const float* Abase = x + (size_t)n0 * DMODEL;
    const float* W0 = Wq + (size_t)o0 * DMODEL;
    const float* W1 = Wk + (size_t)o0 * DMODEL;
    const float* W2 = Wv + (size_t)o0 * DMODEL;

    f32x4 pa[4][2];
    f32x4 pw[3][2];
    if (isA) {
#pragma unroll
        for (int r = 0; r < 4; r++) {
            pa[r][0] = *(const f32x4*)&Abase[(size_t)(asr + r * 32) * DMODEL + asc];
            pa[r][1] = *(const f32x4*)&Abase[(size_t)(asr + r * 32) * DMODEL + asc + 4];
        }
    } else {
        pw[0][0] = *(const f32x4*)&W0[(size_t)wr * DMODEL + wc];
        pw[0][1] = *(const f32x4*)&W0[(size_t)wr * DMODEL + wc + 4];
        pw[1][0] = *(const f32x4*)&W1[(size_t)wr * DMODEL + wc];
        pw[1][1] = *(const f32x4*)&W1[(size_t)wr * DMODEL + wc + 4];
        pw[2][0] = *(const f32x4*)&W2[(size_t)wr * DMODEL + wc];
        pw[2][1] = *(const f32x4*)&W2[(size_t)wr * DMODEL + wc + 4];
    }

    for (int it = 0; it < 8; it++) {
        int p = it & 1;
        if (isA) {
#pragma unroll
            for (int r = 0; r < 4; r++) {
                f16x8 av = {(_Float16)pa[r][0][0], (_Float16)pa[r][0][1],
                            (_Float16)pa[r][0][2], (_Float16)pa[r][0][3],
                            (_Float16)pa[r][1][0], (_Float16)pa[r][1][1],
                            (_Float16)pa[r][1][2], (_Float16)pa[r][1][3]};
                *(f16x8*)&AsB[(size_t)(p * 128 + asr + r * 32) * 64 + axc] = av;
            }
        } else {
#pragma unroll
            for (int zt = 0; zt < 3; zt++) {
                f16x8 wv_ = {(_Float16)pw[zt][0][0], (_Float16)pw[zt][0][1],
                             (_Float16)pw[zt][0][2], (_Float16)pw[zt][0][3],
                             (_Float16)pw[zt][1][0], (_Float16)pw[zt][1][1],
                             (_Float16)pw[zt][1][2], (_Float16)pw[zt][1][3]};
                *(f16x8*)&WsB[(size_t)((p * 3 + zt) * 64 + wr) * 64 + wxc] = wv_;
            }
        }
        __syncthreads();

        int k1 = (it + 1) * 64;
        if (k1 < DMODEL) {
            if (isA) {
#pragma unroll
                for (int r = 0; r < 4; r++) {
                    pa[r][0] = *(const f32x4*)&Abase[(size_t)(asr + r * 32) * DMODEL + k1 + asc];
                    pa[r][1] = *(const f32x4*)&Abase[(size_t)(asr + r * 32) * DMODEL + k1 + asc + 4];
                }
            } else {
                pw[0][0] = *(const f32x4*)&W0[(size_t)wr * DMODEL + k1 + wc];
                pw[0][1] = *(const f32x4*)&W0[(size_t)wr * DMODEL + k1 + wc + 4];
                pw[1][0] = *(const f32x4*)&W1[(size_t)wr * DMODEL + k1 + wc];
                pw[1][1] = *(const f32x4*)&W1[(size_t)wr * DMODEL + k1 + wc + 4];
                pw[2][0] = *(const f32x4*)&W2[(size_t)wr * DMODEL + k1 + wc];
                pw[2][1] = *(const f32x4*)&W2[(size_t)wr * DMODEL + k1 + wc + 4];
            }
        }

#pragma unroll
        for (int ks = 0; ks < 2; ks++) {
            int xc = (ks * 32 + quad * 8) ^ ((ln & 7) << 3);
            f16x8 af0 = *(const f16x8*)&AsB[(size_t)(p * 128 + ww * 32 + ln) * 64 + xc];
            f16x8 af1 = *(const f16x8*)&AsB[(size_t)(p * 128 + ww * 32 + 16 + ln) * 64 + xc];
#pragma unroll
            for (int c = 0; c < 4; c++) {
                f16x8 bf = *(const f16x8*)&WsB[(size_t)((p * 3 + z) * 64 + c * 16 + ln) * 64 + xc];
                acc[0][c] = MFMA16(af0, bf, acc[0][c]);
                acc[1][c] = MFMA16(af1, bf, acc[1][c]);
            }
        }
    }

    __syncthreads();

    const float QS = 0.125f * 1.44269504088896340736f;  // fold log2e -> exp2 in flash
    _Float16* Qs = smem;             // 128x72
    _Float16* Ksep = smem + 9216;    // 128x72
    _Float16* Vt = smem + 18432;     // 64x136

    if (z < 2) {
        _Float16* st = (z == 0) ? Qs : Ksep;
        float sc_ = (z == 0) ? QS : 1.0f;
#pragma unroll
        for (int c = 0; c < 4; c++) {
            float bv_ = biasz[o0 + c * 16 + ln];
#pragma unroll
            for (int rt = 0; rt < 2; rt++)
#pragma unroll
                for (int i = 0; i < 4; i++) {
                    int lr = ww * 32 + rt * 16 + quad * 4 + i;
                    st[(size_t)lr * 72 + c * 16 + ln] =
                        (_Float16)((acc[rt][c][i] + bv_) * sc_);
                }
        }
    } else {
#pragma unroll
        for (int c = 0; c < 4; c++) {
            float bv_ = biasz[o0 + c * 16 + ln];
#pragma unroll
            for (int rt = 0; rt < 2; rt++)
#pragma unroll
                for (int i = 0; i < 4; i++) {
                    // token u64 = (ww&1)*32 + rt*16 + quad*4 + i in 64-group (ww>>1)
                    // stored at pos = sigma^-1(u64) = (ww&1)*32 + quad*8 + rt*4 + i
                    int np = (ww >> 1) * 64 + (ww & 1) * 32 + quad * 8 + rt * 4 + i;
                    Vt[(size_t)(c * 16 + ln) * 136 + np] = (_Float16)(acc[rt][c][i] + bv_);
                }
        }
    }
    __syncthreads();

    if (t < 256) {
#pragma unroll
        for (int k = 0; k < 4; k++) {
            int row = k * 32 + (t >> 3), col = (t & 7) * 8;
            *(f16x8*)&Q16[((size_t)h * N_TOK + n0 + row) * HD + col] =
                *(const f16x8*)&Qs[(size_t)row * 72 + col];
        }
    } else if (t < 512) {
        int u = t - 256;
#pragma unroll
        for (int k = 0; k < 4; k++) {
            int row = k * 32 + (u >> 3), col = (u & 7) * 8;
            *(f16x8*)&K16[((size_t)h * N_TOK + n0 + row) * HD + col] =
                *(const f16x8*)&Ksep[(size_t)row * 72 + col];
        }
    } else {
        int u = t - 512;
#pragma unroll
        for (int k = 0; k < 4; k++) {
            int d = k * 16 + (u >> 4), col = (u & 15) * 8;
            *(f16x8*)&VT16[((size_t)h * HD + d) * N_TOK + n0 + col] =
                *(const f16x8*)&Vt[(size_t)d * 136 + col];
        }
    }
}

// ---------------- flash attention: 1024 thr, 16 waves x 32 rows ---------------
// (exact R8 code — BK=128, 9 barriers, 55.0 us proven)
__global__ __launch_bounds__(1024) void flash_mfma(const _Float16* __restrict__ Q16,
                                                   const _Float16* __restrict__ K16,
                                                   const _Float16* __restrict__ VT16,
                                                   _Float16* __restrict__ OP,
                                                   float* __restrict__ LS) {
    __shared__ __align__(16) _Float16 Ks[2][2][64 * 64];   // 32 KB
    __shared__ __align__(16) _Float16 Vs[2][2][64 * 64];   // 32 KB

    int t = threadIdx.x;
    int w = t >> 6, l = t & 63, quad = l >> 4, ln = l & 15;
    int bid = blockIdx.x;
    int h = bid & 7;
    int qt = (bid >> 3) & 7;
    int s = bid >> 6;
    int q0 = qt * 512 + w * 32;
    int m_start = s * 1024;

    f16x8 qf[2][2];
#pragma unroll
    for (int rt = 0; rt < 2; rt++) {
        const _Float16* qp = &Q16[((size_t)h * N_TOK + q0 + rt * 16 + ln) * HD + quad * 8];
        qf[rt][0] = *(const f16x8*)qp;
        qf[rt][1] = *(const f16x8*)(qp + 32);
    }

    f16x8 ones;
#pragma unroll
    for (int j = 0; j < 8; j++) ones[j] = (_Float16)1.0f;

    f32x4 oacc[2][4] = {};
    f32x4 lacc[2] = {};

    const _Float16* kbase = K16 + (size_t)h * N_TOK * HD;
    const _Float16* vbase = VT16 + (size_t)h * HD * N_TOK;
    int g = t >> 9, tt = t & 511;
    int krow = tt >> 2, kcol = (tt & 3) * 16;
    int vrow = tt >> 3, vcol = (tt & 7) * 16;

    f16x8 pk0, pk1;
    if (g == 0) {
        const _Float16* src = kbase + (size_t)(m_start + krow) * HD + kcol;
        pk0 = *(const f16x8*)src;
        pk1 = *(const f16x8*)(src + 8);
    } else {
        const _Float16* src = vbase + (size_t)vrow * N_TOK + m_start + vcol;
        pk0 = *(const f16x8*)src;
        pk1 = *(const f16x8*)(src + 8);
    }

    for (int it = 0; it < 8; it++) {
        int m0 = m_start + it * 128;
        int p = it & 1;
        if (g == 0) {
            _Float16* dst = &Ks[p][krow >> 6][0];
            int r64 = krow & 63;
            *(f16x8*)&dst[SWZ(r64, kcol)] = pk0;
            *(f16x8*)&dst[SWZ(r64, kcol + 8)] = pk1;
        } else {
            _Float16* dst = &Vs[p][vcol >> 6][0];
            int c64 = vcol & 63;
            *(f16x8*)&dst[SWZ(vrow, c64)] = pk0;
            *(f16x8*)&dst[SWZ(vrow, c64 + 8)] = pk1;
        }
        __syncthreads();

        if (it < 7) {
            int m1 = m0 + 128;
            if (g == 0) {
                const _Float16* src = kbase + (size_t)(m1 + krow) * HD + kcol;
                pk0 = *(const f16x8*)src;
                pk1 = *(const f16x8*)(src + 8);
            } else {
                const _Float16* src = vbase + (size_t)vrow * N_TOK + m1 + vcol;
                pk0 = *(const f16x8*)src;
                pk1 = *(const f16x8*)(src + 8);
            }
        }

#pragma unroll
        for (int kh = 0; kh < 2; kh++) {
            const _Float16* Kt = &Ks[p][kh][0];
            const _Float16* Vt = &Vs[p][kh][0];

            f16x8 kb[4][2], vb[4][2];
#pragma unroll
            for (int c = 0; c < 4; c++) {
                kb[c][0] = *(const f16x8*)&Kt[SWZ(c * 16 + ln, quad * 8)];
                kb[c][1] = *(const f16x8*)&Kt[SWZ(c * 16 + ln, 32 + quad * 8)];
                vb[c][0] = *(const f16x8*)&Vt[SWZ(c * 16 + ln, quad * 8)];
                vb[c][1] = *(const f16x8*)&Vt[SWZ(c * 16 + ln, 32 + quad * 8)];
            }

            f16x8 bf[2][2];
#pragma unroll
            for (int rt = 0; rt < 2; rt++) {
                f32x4 sacc[4] = {};
#pragma unroll
                for (int kk = 0; kk < 4; kk++) {
                    sacc[kk] = MFMA16(kb[kk][0], qf[rt][0], sacc[kk]);
                    sacc[kk] = MFMA16(kb[kk][1], qf[rt][1], sacc[kk]);
                }
#pragma unroll
                for (int kk = 0; kk < 4; kk++) {
                    bf[rt][kk >> 1][(kk & 1) * 4 + 0] = (_Float16)__builtin_exp2f(sacc[kk][0]);
                    bf[rt][kk >> 1][(kk & 1) * 4 + 1] = (_Float16)__builtin_exp2f(sacc[kk][1]);
                    bf[rt][kk >> 1][(kk & 1) * 4 + 2] = (_Float16)__builtin_exp2f(sacc[kk][2]);
                    bf[rt][kk >> 1][(kk & 1) * 4 + 3] = (_Float16)__builtin_exp2f(sacc[kk][3]);
                }
            }

#pragma unroll
            for (int rt = 0; rt < 2; rt++) {
                lacc[rt] = MFMA16(ones, bf[rt][0], lacc[rt]);
                lacc[rt] = MFMA16(ones, bf[rt][1], lacc[rt]);
            }

#pragma unroll
            for (int c = 0; c < 4; c++) {
                oacc[0][c] = MFMA16(vb[c][0], bf[0][0], oacc[0][c]);
                oacc[0][c] = MFMA16(vb[c][1], bf[0][1], oacc[0][c]);
                oacc[1][c] = MFMA16(vb[c][0], bf[1][0], oacc[1][c]);
                oacc[1][c] = MFMA16(vb[c][1], bf[1][1], oacc[1][c]);
            }
        }
    }

    _Float16* obase = OP + (size_t)s * N_TOK * DMODEL;
#pragma unroll
    for (int rt = 0; rt < 2; rt++) {
        int r = q0 + rt * 16 + ln;
#pragma unroll
        for (int c = 0; c < 4; c++) {
            f16x4 ov = {(_Float16)oacc[rt][c][0], (_Float16)oacc[rt][c][1],
                        (_Float16)oacc[rt][c][2], (_Float16)oacc[rt][c][3]};
            *(f16x4*)&obase[(size_t)r * DMODEL + h * HD + c * 16 + quad * 4] = ov;
        }
    }
    if (l < 16) {
#pragma unroll
        for (int rt = 0; rt < 2; rt++) {
            int r = q0 + rt * 16 + ln;
            LS[((size_t)s * NH + h) * N_TOK + r] = lacc[rt][0];
        }
    }
}

// ---------------- output GEMM: 1024 thr, 16 waves, BK=128 (R11) ---------------
// R11: BK 64->128 (4 iters, 5 barriers vs 9) — the lever R8 proved on flash.
// As[2][128][128] (64 KB) + Ws[2][64][128] (32 KB) = 96 KB, SWZ128 layout.
// Per-thread lt head select: (k0+sc)>>6 (16-col slices never straddle a head).
__global__ __launch_bounds__(1024) void out_gemm(const _Float16* __restrict__ OP,
                                                 const float* __restrict__ LS,
                                                 const float* __restrict__ Wo,
                                                 const float* __restrict__ bo,
                                                 float* __restrict__ out) {
    __shared__ __align__(16) _Float16 smem[49152];
    _Float16* AsB = smem;            // [2][128][128] -> 2 x 16384
    _Float16* WsB = smem + 32768;    // [2][64][128]  -> 2 x 8192

    int t = threadIdx.x;
    int w = t >> 6, l = t & 63, quad = l >> 4, ln = l & 15;
    int r16 = w & 7, ch = w >> 3;            // wave row-tile / col-half
    int n0 = blockIdx.x * 128, o0 = blockIdx.y * 64;
    int sr = t >> 3, sc = (t & 7) * 16;      // A: 1 row, 16 cols (2 f16x8)
    int tw = t & 511;
    int wr = tw >> 3, wc = (tw & 7) * 16;    // W: threads<512, 1 row, 16 floats
    bool isW = (t < 512);
    const size_t PSTR = (size_t)N_TOK * DMODEL;

    f32x4 acc[2] = {};

    const float* Wbase = Wo + (size_t)o0 * DMODEL;

    // prefetch k0=0
    f16x8 pa[4][2];
    float lt;
    f32x4 pw[4];
    {
        size_t base = (size_t)(n0 + sr) * DMODEL + sc;
#pragma unroll
        for (int s_ = 0; s_ < 4; s_++) {
            pa[s_][0] = *(const f16x8*)&OP[s_ * PSTR + base];
            pa[s_][1] = *(const f16x8*)&OP[s_ * PSTR + base + 8];
        }
        int hh = sc >> 6;
        const float* ls = LS + (size_t)hh * N_TOK + n0 + sr;
        lt = (ls[0] + ls[NH * N_TOK]) + (ls[2 * NH * N_TOK] + ls[3 * NH * N_TOK]);
        if (isW) {
#pragma unroll
            for (int q_ = 0; q_ < 4; q_++)
                pw[q_] = *(const f32x4*)&Wbase[(size_t)wr * DMODEL + wc + q_ * 4];
        }
    }

    for (int it = 0; it < 4; it++) {
        int p = it & 1;
        {
            float inv = 1.0f / lt;
            f16x8 s0, s1;
#pragma unroll
            for (int j = 0; j < 8; j++) {
                s0[j] = (_Float16)(
                    ((((float)pa[0][0][j] + (float)pa[1][0][j]) +
                      ((float)pa[2][0][j] + (float)pa[3][0][j]))) * inv);
                s1[j] = (_Float16)(
                    ((((float)pa[0][1][j] + (float)pa[1][1][j]) +
                      ((float)pa[2][1][j] + (float)pa[3][1][j]))) * inv);
            }
            *(f16x8*)&AsB[(size_t)p * 16384 + SWZ128(sr, sc)] = s0;
            *(f16x8*)&AsB[(size_t)p * 16384 + SWZ128(sr, sc + 8)] = s1;
            if (isW) {
                f16x8 w0 = {(_Float16)pw[0][0], (_Float16)pw[0][1], (_Float16)pw[0][2],
                            (_Float16)pw[0][3], (_Float16)pw[1][0], (_Float16)pw[1][1],
                            (_Float16)pw[1][2], (_Float16)pw[1][3]};
                f16x8 w1 = {(_Float16)pw[2][0], (_Float16)pw[2][1], (_Float16)pw[2][2],
                            (_Float16)pw[2][3], (_Float16)pw[3][0], (_Float16)pw[3][1],
                            (_Float16)pw[3][2], (_Float16)pw[3][3]};
                *(f16x8*)&WsB[(size_t)p * 8192 + SWZ128(wr, wc)] = w0;
                *(f16x8*)&WsB[(size_t)p * 8192 + SWZ128(wr, wc + 8)] = w1;
            }
        }
        __syncthreads();

        int k1 = (it + 1) * 128;
        if (k1 < DMODEL) {
            size_t base = (size_t)(n0 + sr) * DMODEL + k1 + sc;
#pragma unroll
            for (int s_ = 0; s_ < 4; s_++) {
                pa[s_][0] = *(const f16x8*)&OP[s_ * PSTR + base];
                pa[s_][1] = *(const f16x8*)&OP[s_ * PSTR + base + 8];
            }
            int hh = (k1 + sc) >> 6;
            const float* ls = LS + (size_t)hh * N_TOK + n0 + sr;
            lt = (ls[0] + ls[NH * N_TOK]) + (ls[2 * NH * N_TOK] + ls[3 * NH * N_TOK]);
            if (isW) {
#pragma unroll
                for (int q_ = 0; q_ < 4; q_++)
                    pw[q_] = *(const f32x4*)&Wbase[(size_t)wr * DMODEL + k1 + wc + q_ * 4];
            }
        }

#pragma unroll
        for (int ks = 0; ks < 4; ks++) {
            int cbase = ks * 32 + quad * 8;
            f16x8 af = *(const f16x8*)&AsB[(size_t)p * 16384 + SWZ128(r16 * 16 + ln, cbase)];
#pragma unroll
            for (int c = 0; c < 2; c++) {
                f16x8 bf = *(const f16x8*)&WsB[(size_t)p * 8192 +
                                               SWZ128(ch * 32 + c * 16 + ln, cbase)];
                acc[c] = MFMA16(af, bf, acc[c]);
            }
        }
    }

#pragma unroll
    for (int c = 0; c < 2; c++) {
        float bv_ = bo[o0 + ch * 32 + c * 16 + ln];
#pragma unroll
        for (int i = 0; i < 4; i++) {
            int r = n0 + r16 * 16 + quad * 4 + i;
            out[(size_t)r * DMODEL + o0 + ch * 32 + c * 16 + ln] = acc[c][i] + bv_;
        }
    }
}

extern "C" void kernel_launch(void* const* d_in, const int* in_sizes, int n_in,
                              void* d_out, int out_size, void* d_ws, size_t ws_size,
                              hipStream_t stream) {
    const float* x  = (const float*)d_in[0];
    const float* Wq = (const float*)d_in[1];
    const float* bq = (const float*)d_in[2];
    const float* Wk = (const float*)d_in[3];
    const float* bk = (const float*)d_in[4];
    const float* Wv = (const float*)d_in[5];
    const float* bv = (const float*)d_in[6];
    const float* Wo = (const float*)d_in[7];
    const float* bo = (const float*)d_in[8];
    float* out = (float*)d_out;

    char* ws = (char*)d_ws;
    _Float16* Q16  = (_Float16*)(ws + (4u << 20));       // 4 MB
    _Float16* K16  = (_Float16*)(ws + (8u << 20));       // 4 MB
    _Float16* VT16 = (_Float16*)(ws + (12u << 20));      // 4 MB (key-permuted, sigma)
    _Float16* OP   = (_Float16*)(ws + (16u << 20));      // 16 MB: 4 split-K partials
    float*    LSp  = (float*)   (ws + (32u << 20));      // 512 KB: [4][8][4096]
    // total 32.5 MB

    qkv_gemm<<<dim3(32, 8), 768, 0, stream>>>(x, Wq, bq, Wk, bk, Wv, bv,
                                              Q16, K16, VT16);

    flash_mfma<<<dim3(256), 1024, 0, stream>>>(Q16, K16, VT16, OP, LSp);

    out_gemm<<<dim3(32, 8), 1024, 0, stream>>>(OP, LSp, Wo, bo, out);
}